// Round 12
// baseline (5976.839 us; speedup 1.0000x reference)
//
#include <hip/hip_runtime.h>
#include <math.h>

// Deep ESN, fp32, persistent wavefront-pipelined kernel, round 19.
// R18 (traffic-halving via JW=32 + segment-split producer/consumer blocks)
// died with a container failure -- no counters. Source audit found no
// deadlock (no cyclic wait; guards bounded; co-residency unchanged); the
// plausible on-HW cause is register-pressure spill (dual 128-float acc +
// 32 live weight regs + 8xvf4 pipeline ~ 256 cap) -> scratch per FMA ->
// timeout. R19 = R18 hardened: the two half-column FMA blocks run
// SEQUENTIALLY per iteration, reusing one 16-reg weight vector set
// (live weights 32 -> 16, demand ~200 < 256). All else identical to R18:
// 256 blocks = 4 layers x 32 colgroups x {seg0: own@R_stack, seg1: in@Win},
// each block reads 128KB/tick (32MB/tick total, HALF of R13-R17), seg1
// publishes pre-tanh partials + flag, seg0 polls, combines, tanh, stores.

#define TT    512
#define RDIM  1024
#define EDIM  256
#define NL    4
#define BB    32
#define NBLK  256          // 4 layers x 32 colgroups x 2 segments
#define JW    32           // output columns per block
#define HDIM  (RDIM * NL)  // 4096
#define NPAN  4            // 4 panels of 8 batch rows
#define CSTRIDE 32         // dwords between counter words (128B lines)

#define S_ELEMS   (2 * NL * NPAN * RDIM * 8)   // 2 parities, 1MB
#define PG_ELEMS  (NL * 32 * JW * BB)          // partial buffers, 512KB
#define FIN_ELEMS (BB * HDIM)

typedef float vf2 __attribute__((ext_vector_type(2)));
typedef float vf4 __attribute__((ext_vector_type(4)));

__device__ __forceinline__ float dpp_xor1(float x) {   // lane ^ 1
    return __int_as_float(__builtin_amdgcn_mov_dpp(__float_as_int(x), 0xB1, 0xF, 0xF, true));
}
__device__ __forceinline__ float dpp_xor2(float x) {   // lane ^ 2
    return __int_as_float(__builtin_amdgcn_mov_dpp(__float_as_int(x), 0x4E, 0xF, 0xF, true));
}

// 16B coherent load (bypass L1+L2 -> MALL), issue only, no wait.
__device__ __forceinline__ void gload_sc(vf4& d, const void* p) {
    asm volatile("global_load_dwordx4 %0, %1, off sc0 sc1" : "=v"(d) : "v"(p));
}
// 16B plain cached load (xe: read-only input, L2-cacheable), issue only.
__device__ __forceinline__ void gload_pl(vf4& d, const void* p) {
    asm volatile("global_load_dwordx4 %0, %1, off" : "=v"(d) : "v"(p));
}
// Counted wait, data-tied to the buffer being consumed.
__device__ __forceinline__ void vwait(int wn, vf4& r) {
    if (wn >= 7)      asm volatile("s_waitcnt vmcnt(7)" : "+v"(r));
    else if (wn == 6) asm volatile("s_waitcnt vmcnt(6)" : "+v"(r));
    else if (wn == 5) asm volatile("s_waitcnt vmcnt(5)" : "+v"(r));
    else if (wn == 4) asm volatile("s_waitcnt vmcnt(4)" : "+v"(r));
    else if (wn == 3) asm volatile("s_waitcnt vmcnt(3)" : "+v"(r));
    else if (wn == 2) asm volatile("s_waitcnt vmcnt(2)" : "+v"(r));
    else if (wn == 1) asm volatile("s_waitcnt vmcnt(1)" : "+v"(r));
    else              asm volatile("s_waitcnt vmcnt(0)" : "+v"(r));
}

// ---------------------------------------------------------------- gather ----
// xe[t][panel][k][8b] : panel layout matching reservoir reads
__global__ void gather_kernel(const int* __restrict__ x,
                              const float* __restrict__ embed,
                              float* __restrict__ xe)
{
    __shared__ int   ids[BB];
    __shared__ float sh[BB * (EDIM + 1)];
    const int t = blockIdx.x, tid = threadIdx.x;
    if (tid < BB) ids[tid] = x[tid * TT + t];
    __syncthreads();
    for (int r = 0; r < BB; ++r)
        sh[r * (EDIM + 1) + tid] = embed[ids[r] * EDIM + tid];
    __syncthreads();
    for (int i = tid; i < NPAN * EDIM * 8; i += 256) {
        int p = i >> 11, k = (i >> 3) & (EDIM - 1), bo = i & 7;
        xe[(size_t)t * (NPAN * EDIM * 8) + i] = sh[(p * 8 + bo) * (EDIM + 1) + k];
    }
}

// ------------------------------------------------- per-tick compute body ----
// One K-segment, NI iters/wave, depth-8 pipelined loads. The two column
// halves are processed SEQUENTIALLY per iteration to halve live weight regs.
template<int NI, bool SCIN>
__device__ __forceinline__ void tick_body(
    const float* __restrict__ Ssrc, const float* __restrict__ Wlds,
    const int kh, const int lam, const int kq, const int bh,
    vf2 acc0[4][8], vf2 acc1[4][8])
{
    const vf4* sp = (const vf4*)Ssrc;
    vf4 b[8];
    constexpr int PRO = (NI < 8) ? NI : 8;

    #pragma unroll
    for (int i = 0; i < PRO; ++i) {
        const void* p = (const void*)(sp + (size_t)(kh * NI + i) * 64 + lam);
        if (SCIN) gload_sc(b[i], p); else gload_pl(b[i], p);
    }

    #pragma unroll
    for (int i = 0; i < NI; ++i) {
        vf4& br = b[i & 7];
        const int wn = (NI - 1 - i) < 7 ? (NI - 1 - i) : 7;
        vwait(wn, br);
        const vf4 v = br;
        if (i + 8 < NI) {
            const void* p = (const void*)(sp + (size_t)(kh * NI + i + 8) * 64 + lam);
            if (SCIN) gload_sc(br, p); else gload_pl(br, p);
        }
        const int krow = (kh * NI + i) * 32 + kq;
        const float* wr = &Wlds[krow * JW];
        const float vv[4] = {v[0], v[1], v[2], v[3]};
        {   // ---- columns 0..15 ----
            float4 a0 = *(const float4*)(wr + bh * 8);
            float4 a1 = *(const float4*)(wr + bh * 8 + 4);
            vf2 wv[8];
            wv[0] = (vf2){a0.x, a0.y}; wv[1] = (vf2){a0.z, a0.w};
            wv[2] = (vf2){a1.x, a1.y}; wv[3] = (vf2){a1.z, a1.w};
            wv[4] = (vf2){dpp_xor1(a0.x), dpp_xor1(a0.y)};
            wv[5] = (vf2){dpp_xor1(a0.z), dpp_xor1(a0.w)};
            wv[6] = (vf2){dpp_xor1(a1.x), dpp_xor1(a1.y)};
            wv[7] = (vf2){dpp_xor1(a1.z), dpp_xor1(a1.w)};
            #pragma unroll
            for (int q = 0; q < 4; ++q) {
                vf2 s = {vv[q], vv[q]};
                #pragma unroll
                for (int jp = 0; jp < 8; ++jp) acc0[q][jp] += s * wv[jp];
            }
        }
        {   // ---- columns 16..31 (reuse the same weight registers) ----
            float4 c0 = *(const float4*)(wr + 16 + bh * 8);
            float4 c1 = *(const float4*)(wr + 16 + bh * 8 + 4);
            vf2 wv[8];
            wv[0] = (vf2){c0.x, c0.y}; wv[1] = (vf2){c0.z, c0.w};
            wv[2] = (vf2){c1.x, c1.y}; wv[3] = (vf2){c1.z, c1.w};
            wv[4] = (vf2){dpp_xor1(c0.x), dpp_xor1(c0.y)};
            wv[5] = (vf2){dpp_xor1(c0.z), dpp_xor1(c0.w)};
            wv[6] = (vf2){dpp_xor1(c1.x), dpp_xor1(c1.y)};
            wv[7] = (vf2){dpp_xor1(c1.z), dpp_xor1(c1.w)};
            #pragma unroll
            for (int q = 0; q < 4; ++q) {
                vf2 s = {vv[q], vv[q]};
                #pragma unroll
                for (int jp = 0; jp < 8; ++jp) acc1[q][jp] += s * wv[jp];
            }
        }
    }
}

// ---- reduce-scatter over kq: 64 accs -> 2 finals per lane (verified map) ----
__device__ __forceinline__ void reduce64(const vf2 acc[4][8], const int kq,
                                         float rfin[2])
{
    float r64v[64];
    #pragma unroll
    for (int i = 0; i < 4; ++i)
        #pragma unroll
        for (int jp = 0; jp < 8; ++jp) {
            r64v[(i << 4) | (jp << 1)]     = acc[i][jp].x;
            r64v[(i << 4) | (jp << 1) | 1] = acc[i][jp].y;
        }
    float r32v[32], r16v[16], r8v[8], r4v[4];
    {   const bool myb = kq & 1;
        #pragma unroll
        for (int m = 0; m < 32; ++m) {
            float a = r64v[2 * m], b = r64v[2 * m + 1];
            float send = myb ? a : b, keep = myb ? b : a;
            r32v[m] = keep + dpp_xor2(send);
        }
    }
    {   const bool myb = (kq >> 1) & 1;
        #pragma unroll
        for (int m = 0; m < 16; ++m) {
            float a = r32v[2 * m], b = r32v[2 * m + 1];
            float send = myb ? a : b, keep = myb ? b : a;
            r16v[m] = keep + __shfl_xor(send, 4, 64);
        }
    }
    {   const bool myb = (kq >> 2) & 1;
        #pragma unroll
        for (int m = 0; m < 8; ++m) {
            float a = r16v[2 * m], b = r16v[2 * m + 1];
            float send = myb ? a : b, keep = myb ? b : a;
            r8v[m] = keep + __shfl_xor(send, 8, 64);
        }
    }
    {   const bool myb = (kq >> 3) & 1;
        #pragma unroll
        for (int m = 0; m < 4; ++m) {
            float a = r8v[2 * m], b = r8v[2 * m + 1];
            float send = myb ? a : b, keep = myb ? b : a;
            r4v[m] = keep + __shfl_xor(send, 16, 64);
        }
    }
    {   const bool myb = (kq >> 4) & 1;
        #pragma unroll
        for (int m = 0; m < 2; ++m) {
            float a = r4v[2 * m], b = r4v[2 * m + 1];
            float send = myb ? a : b, keep = myb ? b : a;
            rfin[m] = keep + __shfl_xor(send, 32, 64);
        }
    }
}

// ------------------------------------------------------------- reservoir ----
__global__ __launch_bounds__(512, 2) void reservoir_kernel(
    const float* __restrict__ Win0, const float* __restrict__ WinR,
    const float* __restrict__ Rst,  const float* __restrict__ xe,
    float* __restrict__ S, float* __restrict__ Pglob, float* __restrict__ Fin,
    unsigned* __restrict__ cnt, unsigned* __restrict__ rel,
    unsigned* __restrict__ flagP)
{
    __shared__ float Wlds[RDIM * JW];        // 128 KB max (seg weights)
    __shared__ float Pbuf[NPAN * JW * 8];    // 4 KB, cross-wave kh partials
    const int tid   = threadIdx.x;
    const int blk   = blockIdx.x;
    const int layer = blk >> 6;
    const int r     = blk & 63;
    const int seg   = r >> 5;               // 0: own@R_stack, 1: input@Win
    const int g     = r & 31;               // colgroup
    const int j0    = g * JW;
    const int KSEG  = (seg == 0) ? RDIM : (layer == 0 ? EDIM : RDIM);

    // stage this segment's weight col-slice: [KSEG][32]
    for (int idx = tid; idx < KSEG * JW; idx += 512) {
        int k = idx >> 5, j = idx & 31;
        float wv;
        if (seg == 0) wv = Rst[((size_t)layer * RDIM + k) * RDIM + j0 + j];
        else          wv = (layer == 0) ? Win0[(size_t)k * RDIM + j0 + j]
                                        : WinR[((size_t)(layer - 1) * RDIM + k) * RDIM + j0 + j];
        Wlds[idx] = wv;
    }
    __syncthreads();

    const int w8  = tid >> 6;   // 8 waves
    const int w   = w8 & 3;     // panel (8 batch rows)
    const int kh  = w8 >> 2;    // k-half of this segment
    const int lam = tid & 63;
    const int kq  = lam >> 1;
    const int bh  = lam & 1;
    const int bh4 = bh * 4;
    const int pgi = layer * 32 + g;         // partial-buffer / flag index
    float* const pg = Pglob + (size_t)pgi * (JW * BB);

    for (int tick = 0; tick < TT + NL - 1; ++tick) {
        const int t = tick - layer;
        if (t >= 0 && t < TT) {
            const int cur = tick & 1, prv = (tick - 1) & 1;

            vf2 acc0[4][8], acc1[4][8];
            #pragma unroll
            for (int i = 0; i < 4; ++i)
                #pragma unroll
                for (int jp = 0; jp < 8; ++jp) {
                    acc0[i][jp] = (vf2)(0.f); acc1[i][jp] = (vf2)(0.f);
                }

            if (seg == 0) {
                const float* Ssrc = S + (((size_t)(prv * NL + layer)) * NPAN + w) * RDIM * 8;
                tick_body<16, true>(Ssrc, Wlds, kh, lam, kq, bh, acc0, acc1);
            } else if (layer == 0) {
                const float* Ssrc = xe + ((size_t)t * NPAN + w) * (EDIM * 8);
                tick_body<4, false>(Ssrc, Wlds, kh, lam, kq, bh, acc0, acc1);
            } else {
                const float* Ssrc = S + (((size_t)(prv * NL + layer - 1)) * NPAN + w) * RDIM * 8;
                tick_body<16, true>(Ssrc, Wlds, kh, lam, kq, bh, acc0, acc1);
            }

            float rf0[2], rf1[2];
            reduce64(acc0, kq, rf0);
            reduce64(acc1, kq, rf1);

            // ---- cross-wave kh combine via LDS ----
            const int i0 = kq >> 4;
            const int cc = kq & 15;
            const int jb = (cc & 7) + 8 * (bh ^ (cc >> 3));   // col within half
            if (kh) {
                #pragma unroll
                for (int m = 0; m < 2; ++m) {
                    Pbuf[(w * JW + jb) * 8 + (bh4 + i0 + 2 * m)]      = rf0[m];
                    Pbuf[(w * JW + 16 + jb) * 8 + (bh4 + i0 + 2 * m)] = rf1[m];
                }
            }
            __syncthreads();

            if (seg == 1) {
                // producer: publish partials (pre-tanh) to Pglob + flag
                if (!kh) {
                    #pragma unroll
                    for (int m = 0; m < 2; ++m) {
                        const int bi = bh4 + i0 + 2 * m;
                        float p0 = rf0[m] + Pbuf[(w * JW + jb) * 8 + bi];
                        float p1 = rf1[m] + Pbuf[(w * JW + 16 + jb) * 8 + bi];
                        __hip_atomic_store(&pg[(size_t)jb * BB + w * 8 + bi], p0,
                                           __ATOMIC_RELAXED, __HIP_MEMORY_SCOPE_AGENT);
                        __hip_atomic_store(&pg[(size_t)(16 + jb) * BB + w * 8 + bi], p1,
                                           __ATOMIC_RELAXED, __HIP_MEMORY_SCOPE_AGENT);
                    }
                }
                __syncthreads();                 // drains partial stores
                if (tid == 0)
                    __hip_atomic_store(&flagP[pgi * CSTRIDE], (unsigned)(tick + 1),
                                       __ATOMIC_RELAXED, __HIP_MEMORY_SCOPE_AGENT);
            } else {
                // consumer: wait for producer's partials, combine, tanh, store
                if (tid == 0) {
                    int guard = 0;
                    while (__hip_atomic_load(&flagP[pgi * CSTRIDE],
                                             __ATOMIC_RELAXED, __HIP_MEMORY_SCOPE_AGENT)
                           < (unsigned)(tick + 1)) {
                        __builtin_amdgcn_s_sleep(2);
                        if (++guard > (1 << 18)) break;   // safety valve
                    }
                }
                __syncthreads();
                if (!kh) {
                    float v0[2], v1[2], q0[2], q1[2];
                    #pragma unroll
                    for (int m = 0; m < 2; ++m) {
                        const int bi = bh4 + i0 + 2 * m;
                        v0[m] = rf0[m] + Pbuf[(w * JW + jb) * 8 + bi];
                        v1[m] = rf1[m] + Pbuf[(w * JW + 16 + jb) * 8 + bi];
                        q0[m] = __uint_as_float(__hip_atomic_load(
                                  (const unsigned*)&pg[(size_t)jb * BB + w * 8 + bi],
                                  __ATOMIC_RELAXED, __HIP_MEMORY_SCOPE_AGENT));
                        q1[m] = __uint_as_float(__hip_atomic_load(
                                  (const unsigned*)&pg[(size_t)(16 + jb) * BB + w * 8 + bi],
                                  __ATOMIC_RELAXED, __HIP_MEMORY_SCOPE_AGENT));
                    }
                    float* sbase = S + (((size_t)(cur * NL + layer)) * NPAN + w) * RDIM * 8;
                    #pragma unroll
                    for (int m = 0; m < 2; ++m) {
                        const int bi = bh4 + i0 + 2 * m;
                        const float o0 = tanhf(v0[m] + q0[m]);
                        const float o1 = tanhf(v1[m] + q1[m]);
                        __hip_atomic_store(sbase + (size_t)(j0 + jb) * 8 + bi, o0,
                                           __ATOMIC_RELAXED, __HIP_MEMORY_SCOPE_AGENT);
                        __hip_atomic_store(sbase + (size_t)(j0 + 16 + jb) * 8 + bi, o1,
                                           __ATOMIC_RELAXED, __HIP_MEMORY_SCOPE_AGENT);
                        if (t == TT - 1) {
                            Fin[(size_t)(w * 8 + bi) * HDIM + layer * RDIM + j0 + jb]      = o0;
                            Fin[(size_t)(w * 8 + bi) * HDIM + layer * RDIM + j0 + 16 + jb] = o1;
                        }
                    }
                }
            }
        }
        // ---- grid barrier v3: spread arrive, single summer, replicated
        //      release lines, 1-lane backoff polls ----
        __syncthreads();                          // drains all waves' stores
        if (tid == 0)
            __hip_atomic_fetch_add(&cnt[(blk & 15) * CSTRIDE], 1u,
                                   __ATOMIC_RELAXED, __HIP_MEMORY_SCOPE_AGENT);
        const unsigned wrel = (unsigned)(tick + 1);
        if (blk == 0) {
            if (tid < 64) {                       // summer wave
                const unsigned wsum = wrel * (unsigned)NBLK;
                int guard = 0;
                for (;;) {
                    unsigned v = 0;
                    if (lam < 16)
                        v = __hip_atomic_load(&cnt[lam * CSTRIDE],
                                              __ATOMIC_RELAXED, __HIP_MEMORY_SCOPE_AGENT);
                    #pragma unroll
                    for (int m = 1; m <= 32; m <<= 1) v += __shfl_xor(v, m, 64);
                    if (v >= wsum) break;         // v is total on ALL lanes
                    __builtin_amdgcn_s_sleep(2);
                    if (++guard > (1 << 16)) break;   // safety valve
                }
                if (lam < 16)                     // publish release, 16 copies
                    __hip_atomic_store(&rel[lam * CSTRIDE], wrel,
                                       __ATOMIC_RELAXED, __HIP_MEMORY_SCOPE_AGENT);
            }
        } else {
            if (tid == 0) {                       // one poller lane per block
                int guard = 0;
                while (__hip_atomic_load(&rel[(blk & 15) * CSTRIDE],
                                         __ATOMIC_RELAXED, __HIP_MEMORY_SCOPE_AGENT) < wrel) {
                    __builtin_amdgcn_s_sleep(4);
                    if (++guard > (1 << 16)) break;   // safety valve
                }
            }
        }
        __syncthreads();
    }
}

// ------------------------------------------------------------- layernorm ----
__global__ void ln_kernel(const float* __restrict__ Fin,
                          const float* __restrict__ gamma,
                          const float* __restrict__ beta,
                          float* __restrict__ out)
{
    const int r = blockIdx.x, tid = threadIdx.x;
    const float* row = Fin + (size_t)r * HDIM;
    float s = 0.f, s2 = 0.f;
    for (int i = tid; i < HDIM; i += 256) { float v = row[i]; s += v; s2 += v * v; }
    for (int off = 32; off; off >>= 1) {
        s  += __shfl_down(s,  off, 64);
        s2 += __shfl_down(s2, off, 64);
    }
    __shared__ float rs[4], rs2[4];
    __shared__ float mu_s, rstd_s;
    if ((tid & 63) == 0) { rs[tid >> 6] = s; rs2[tid >> 6] = s2; }
    __syncthreads();
    if (tid == 0) {
        float S1 = rs[0] + rs[1] + rs[2] + rs[3];
        float S2 = rs2[0] + rs2[1] + rs2[2] + rs2[3];
        float mu = S1 / (float)HDIM;
        float var = S2 / (float)HDIM - mu * mu;
        mu_s = mu; rstd_s = rsqrtf(var + 1e-5f);
    }
    __syncthreads();
    float mu = mu_s, rstd = rstd_s;
    for (int i = tid; i < HDIM; i += 256)
        out[(size_t)r * HDIM + i] = (row[i] - mu) * rstd * gamma[i] + beta[i];
}

// ----------------------------------------------------------------- launch ---
extern "C" void kernel_launch(void* const* d_in, const int* in_sizes, int n_in,
                              void* d_out, int out_size, void* d_ws, size_t ws_size,
                              hipStream_t stream)
{
    const int*   x     = (const int*)d_in[0];
    const float* embed = (const float*)d_in[1];
    const float* Win0  = (const float*)d_in[2];
    const float* WinR  = (const float*)d_in[3];
    const float* Rst   = (const float*)d_in[4];
    const float* gamma = (const float*)d_in[5];
    const float* beta  = (const float*)d_in[6];
    float* out = (float*)d_out;

    char* ws = (char*)d_ws;
    unsigned* cnt   = (unsigned*)ws;                    // 16 lines (arrive)
    unsigned* rel   = cnt + 16 * CSTRIDE;               // 16 lines (release)
    unsigned* flagP = (unsigned*)(ws + 4096);           // 128 lines (partials)
    float* S     = (float*)(ws + 24576);                               // 1MB
    float* Pglob = S + S_ELEMS;                                        // 512KB
    float* Fin   = Pglob + PG_ELEMS;                                   // 512KB
    float* xe    = Fin + FIN_ELEMS;                                    // 16.8MB

    hipMemsetAsync(ws, 0, 24576 + (size_t)S_ELEMS * 4, stream);   // flags+states
    gather_kernel   <<<TT,   256, 0, stream>>>(x, embed, xe);
    reservoir_kernel<<<NBLK, 512, 0, stream>>>(Win0, WinR, Rst, xe, S, Pglob, Fin,
                                               cnt, rel, flagP);
    ln_kernel       <<<BB,   256, 0, stream>>>(Fin, gamma, beta, out);
}

// Round 13
// 5171.109 us; speedup vs baseline: 1.1558x; 1.1558x over previous
//
#include <hip/hip_runtime.h>
#include <math.h>

// Deep ESN, fp32, persistent wavefront-pipelined kernel, round 20.
// R19 falsified the coherent-BW theory (halving traffic REGRESSED: the
// producer/consumer hop serialized each tick). All nulls point one way:
// the only lever that ever paid is waves/SIMD (R7->R8: 1->2 = +22%).
// R20 reaches 4 waves/SIMD without the 1024-thread VGPR-64 trap:
//   JW 16->8  => weight slice 64KB (+1KB Pbuf) => 2 blocks/CU in LDS.
//   Grid 512 = 4 layers x 128 colgroups, exactly 2/CU co-resident.
//   __launch_bounds__(512,4) caps VGPR at 128 -> residency guaranteed.
// Per-SIMD FMA work unchanged (per-wave work halves, waves double); MLP
// doubles. JW=8 drops the DPP weight broadcast (lane reads all 8 cols) and
// acc shrinks to 32 floats. Reduce = 5-stage 32->1 (same ladder as the
// verified 64->2, one fewer surviving value). Coherent traffic doubles to
// 128MB/tick -- R19 says we had >=2x rate headroom; this tests it.

#define TT    512
#define RDIM  1024
#define EDIM  256
#define NL    4
#define BB    32
#define NBLK  512          // 4 layers x 128 colgroups
#define JW    8            // output columns per block
#define HDIM  (RDIM * NL)  // 4096
#define NPAN  4            // 4 panels of 8 batch rows
#define CSTRIDE 32         // dwords between counter words (128B lines)

#define S_ELEMS   (2 * NL * NPAN * RDIM * 8)   // 2 parities, 1MB
#define FIN_ELEMS (BB * HDIM)

typedef float vf2 __attribute__((ext_vector_type(2)));
typedef float vf4 __attribute__((ext_vector_type(4)));

__device__ __forceinline__ float dpp_xor2(float x) {   // lane ^ 2
    return __int_as_float(__builtin_amdgcn_mov_dpp(__float_as_int(x), 0x4E, 0xF, 0xF, true));
}

// 16B coherent load (bypass L1+L2 -> MALL), issue only, no wait.
__device__ __forceinline__ void gload_sc(vf4& d, const void* p) {
    asm volatile("global_load_dwordx4 %0, %1, off sc0 sc1" : "=v"(d) : "v"(p));
}
// 16B plain cached load (xe: read-only input, L2-cacheable), issue only.
__device__ __forceinline__ void gload_pl(vf4& d, const void* p) {
    asm volatile("global_load_dwordx4 %0, %1, off" : "=v"(d) : "v"(p));
}
// Counted wait, data-tied to the buffer being consumed.
__device__ __forceinline__ void vwait(int wn, vf4& r) {
    if (wn >= 7)      asm volatile("s_waitcnt vmcnt(7)" : "+v"(r));
    else if (wn == 6) asm volatile("s_waitcnt vmcnt(6)" : "+v"(r));
    else if (wn == 5) asm volatile("s_waitcnt vmcnt(5)" : "+v"(r));
    else if (wn == 4) asm volatile("s_waitcnt vmcnt(4)" : "+v"(r));
    else if (wn == 3) asm volatile("s_waitcnt vmcnt(3)" : "+v"(r));
    else if (wn == 2) asm volatile("s_waitcnt vmcnt(2)" : "+v"(r));
    else if (wn == 1) asm volatile("s_waitcnt vmcnt(1)" : "+v"(r));
    else              asm volatile("s_waitcnt vmcnt(0)" : "+v"(r));
}

// ---------------------------------------------------------------- gather ----
// xe[t][panel][k][8b] : panel layout matching reservoir reads
__global__ void gather_kernel(const int* __restrict__ x,
                              const float* __restrict__ embed,
                              float* __restrict__ xe)
{
    __shared__ int   ids[BB];
    __shared__ float sh[BB * (EDIM + 1)];
    const int t = blockIdx.x, tid = threadIdx.x;
    if (tid < BB) ids[tid] = x[tid * TT + t];
    __syncthreads();
    for (int r = 0; r < BB; ++r)
        sh[r * (EDIM + 1) + tid] = embed[ids[r] * EDIM + tid];
    __syncthreads();
    for (int i = tid; i < NPAN * EDIM * 8; i += 256) {
        int p = i >> 11, k = (i >> 3) & (EDIM - 1), bo = i & 7;
        xe[(size_t)t * (NPAN * EDIM * 8) + i] = sh[(p * 8 + bo) * (EDIM + 1) + k];
    }
}

// ------------------------------------------------- per-tick compute body ----
// Depth-8 pipelined MALL loads; JW=8 so each lane reads all 8 weight cols
// directly (no DPP broadcast). acc[q][jp] = batch (bh*4+q) x cols (2jp,2jp+1).
template<int NI, bool SCIN>
__device__ __forceinline__ void tick_body(
    const float* __restrict__ Sown, const float* __restrict__ Sin,
    const float* __restrict__ Wlds,
    const int kh, const int lam, const int kq,
    vf2 acc[4][4])
{
    constexpr int NOWN = 16;            // per-wave own iters (K=1024 kh-split)
    constexpr int NT   = NOWN + NI;

    const vf4* ownp = (const vf4*)Sown;
    const vf4* inp  = (const vf4*)Sin;

    vf4 b[8];

    #pragma unroll
    for (int i = 0; i < 8; ++i)
        gload_sc(b[i], (const void*)(ownp + (size_t)(kh * NOWN + i) * 64 + lam));

    #pragma unroll
    for (int i = 0; i < NT; ++i) {
        vf4& br = b[i & 7];
        const int wn = (NT - 1 - i) < 7 ? (NT - 1 - i) : 7;
        vwait(wn, br);
        const vf4 v = br;
        if (i + 8 < NT) {
            const int n = i + 8;
            if (n < NOWN) {
                gload_sc(br, (const void*)(ownp + (size_t)(kh * NOWN + n) * 64 + lam));
            } else {
                const void* p = (const void*)(inp + (size_t)(kh * NI + (n - NOWN)) * 64 + lam);
                if (SCIN) gload_sc(br, p);
                else      gload_pl(br, p);
            }
        }
        const int krow = (i < NOWN) ? ((kh * NOWN + i) * 32 + kq)
                                    : (RDIM + (kh * NI + (i - NOWN)) * 32 + kq);
        const float* wr = &Wlds[krow * JW];
        float4 a0 = *(const float4*)wr;
        float4 a1 = *(const float4*)(wr + 4);
        vf2 wv[4];
        wv[0] = (vf2){a0.x, a0.y}; wv[1] = (vf2){a0.z, a0.w};
        wv[2] = (vf2){a1.x, a1.y}; wv[3] = (vf2){a1.z, a1.w};
        const float vv[4] = {v[0], v[1], v[2], v[3]};
        #pragma unroll
        for (int q = 0; q < 4; ++q) {
            vf2 s = {vv[q], vv[q]};
            #pragma unroll
            for (int jp = 0; jp < 4; ++jp) acc[q][jp] += s * wv[jp];
        }
    }
}

// ---- reduce-scatter over kq: 32 accs -> 1 final per lane ----
// Same ladder as the verified 64->2 reduce, one fewer surviving value.
// Final lane (kq,bh) holds output: col = 2*(2*kq[2]+kq[1]) + kq[0],
//                                  bi  = bh*4 + 2*kq[4] + kq[3].
__device__ __forceinline__ float reduce32(const vf2 acc[4][4], const int kq)
{
    float r32v[32];
    #pragma unroll
    for (int q = 0; q < 4; ++q)
        #pragma unroll
        for (int jp = 0; jp < 4; ++jp) {
            r32v[(q << 3) | (jp << 1)]     = acc[q][jp].x;
            r32v[(q << 3) | (jp << 1) | 1] = acc[q][jp].y;
        }
    float r16v[16], r8v[8], r4v[4], r2v[2], rfin;
    {   const bool myb = kq & 1;                 // stage 0: DPP xor2
        #pragma unroll
        for (int m = 0; m < 16; ++m) {
            float a = r32v[2 * m], b = r32v[2 * m + 1];
            float send = myb ? a : b, keep = myb ? b : a;
            r16v[m] = keep + dpp_xor2(send);
        }
    }
    {   const bool myb = (kq >> 1) & 1;          // stage 1: xor 4
        #pragma unroll
        for (int m = 0; m < 8; ++m) {
            float a = r16v[2 * m], b = r16v[2 * m + 1];
            float send = myb ? a : b, keep = myb ? b : a;
            r8v[m] = keep + __shfl_xor(send, 4, 64);
        }
    }
    {   const bool myb = (kq >> 2) & 1;          // stage 2: xor 8
        #pragma unroll
        for (int m = 0; m < 4; ++m) {
            float a = r8v[2 * m], b = r8v[2 * m + 1];
            float send = myb ? a : b, keep = myb ? b : a;
            r4v[m] = keep + __shfl_xor(send, 8, 64);
        }
    }
    {   const bool myb = (kq >> 3) & 1;          // stage 3: xor 16
        #pragma unroll
        for (int m = 0; m < 2; ++m) {
            float a = r4v[2 * m], b = r4v[2 * m + 1];
            float send = myb ? a : b, keep = myb ? b : a;
            r2v[m] = keep + __shfl_xor(send, 16, 64);
        }
    }
    {   const bool myb = (kq >> 4) & 1;          // stage 4: xor 32
        float a = r2v[0], b = r2v[1];
        float send = myb ? a : b, keep = myb ? b : a;
        rfin = keep + __shfl_xor(send, 32, 64);
    }
    return rfin;
}

// ------------------------------------------------------------- reservoir ----
__global__ __launch_bounds__(512, 4) void reservoir_kernel(
    const float* __restrict__ Win0, const float* __restrict__ WinR,
    const float* __restrict__ Rst,  const float* __restrict__ xe,
    float* __restrict__ S, float* __restrict__ Fin,
    unsigned* __restrict__ cnt, unsigned* __restrict__ rel)
{
    __shared__ float Wlds[2048 * JW];       // 64 KB, row k = 8 floats
    __shared__ float Pbuf[NPAN * JW * 8];   // 1 KB, cross-wave kh partials
    const int tid   = threadIdx.x;
    const int blk   = blockIdx.x;
    const int layer = blk >> 7;
    const int g     = blk & 127;            // colgroup
    const int j0    = g * JW;
    const int Kin   = (layer == 0) ? EDIM : RDIM;

    // rows [0,1024) = R_stack col-slice, rows [1024,1024+Kin) = Win col-slice
    for (int idx = tid; idx < (RDIM + Kin) * JW; idx += 512) {
        int k = idx >> 3, j = idx & 7;
        float wv;
        if (k < RDIM) wv = Rst[((size_t)layer * RDIM + k) * RDIM + j0 + j];
        else {
            int k2 = k - RDIM;
            wv = (layer == 0) ? Win0[(size_t)k2 * RDIM + j0 + j]
                              : WinR[((size_t)(layer - 1) * RDIM + k2) * RDIM + j0 + j];
        }
        Wlds[idx] = wv;
    }
    __syncthreads();

    const int w8  = tid >> 6;   // 8 waves
    const int w   = w8 & 3;     // panel (8 batch rows)
    const int kh  = w8 >> 2;    // k-half: wave reads a disjoint k-slice
    const int lam = tid & 63;
    const int kq  = lam >> 1;   // 32-way k split within wave
    const int bh  = lam & 1;    // which float4 of the 8-wide batch row
    // final-output mapping (from the reduce32 ladder)
    const int col = 2 * (2 * ((kq >> 2) & 1) + ((kq >> 1) & 1)) + (kq & 1);
    const int bi  = bh * 4 + 2 * ((kq >> 4) & 1) + ((kq >> 3) & 1);

    for (int tick = 0; tick < TT + NL - 1; ++tick) {
        const int t = tick - layer;
        if (t >= 0 && t < TT) {
            const int cur = tick & 1, prv = (tick - 1) & 1;
            const float* Sown = S + (((size_t)(prv * NL + layer)) * NPAN + w) * RDIM * 8;
            const float* Sin  = (layer == 0)
                ? (xe + ((size_t)t * NPAN + w) * (EDIM * 8))
                : (S + (((size_t)(prv * NL + layer - 1)) * NPAN + w) * RDIM * 8);

            vf2 acc[4][4];
            #pragma unroll
            for (int i = 0; i < 4; ++i)
                #pragma unroll
                for (int jp = 0; jp < 4; ++jp) acc[i][jp] = (vf2)(0.f);

            if (layer == 0) tick_body<4,  false>(Sown, Sin, Wlds, kh, lam, kq, acc);
            else            tick_body<16, true >(Sown, Sin, Wlds, kh, lam, kq, acc);

            const float rf = reduce32(acc, kq);

            // ---- cross-wave k-half combine via LDS, then epilogue ----
            if (kh)                                 // k-half 1: publish partial
                Pbuf[(w * JW + col) * 8 + bi] = rf;
            __syncthreads();                        // block-uniform (t uniform)
            if (!kh) {                              // k-half 0: combine + store
                const float o = tanhf(rf + Pbuf[(w * JW + col) * 8 + bi]);
                float* sdst = S + (((size_t)(cur * NL + layer)) * NPAN + w) * RDIM * 8
                                + (size_t)(j0 + col) * 8 + bi;
                // sc1 store: direct to MALL, drained by pre-barrier vmcnt(0)
                __hip_atomic_store(sdst, o, __ATOMIC_RELAXED, __HIP_MEMORY_SCOPE_AGENT);
                if (t == TT - 1)
                    Fin[(size_t)(w * 8 + bi) * HDIM + layer * RDIM + j0 + col] = o;
            }
        }
        // ---- grid barrier v3: spread arrive, single summer, replicated
        //      release lines, 1-lane backoff polls (no poll storm) ----
        __syncthreads();                          // drains all waves' stores
        if (tid == 0)
            __hip_atomic_fetch_add(&cnt[(blk & 15) * CSTRIDE], 1u,
                                   __ATOMIC_RELAXED, __HIP_MEMORY_SCOPE_AGENT);
        const unsigned wrel = (unsigned)(tick + 1);
        if (blk == 0) {
            if (tid < 64) {                       // summer wave
                const unsigned wsum = wrel * (unsigned)NBLK;
                int guard = 0;
                for (;;) {
                    unsigned v = 0;
                    if (lam < 16)
                        v = __hip_atomic_load(&cnt[lam * CSTRIDE],
                                              __ATOMIC_RELAXED, __HIP_MEMORY_SCOPE_AGENT);
                    #pragma unroll
                    for (int m = 1; m <= 32; m <<= 1) v += __shfl_xor(v, m, 64);
                    if (v >= wsum) break;         // v is total on ALL lanes
                    __builtin_amdgcn_s_sleep(2);
                    if (++guard > (1 << 17)) break;   // safety valve
                }
                if (lam < 16)                     // publish release, 16 copies
                    __hip_atomic_store(&rel[lam * CSTRIDE], wrel,
                                       __ATOMIC_RELAXED, __HIP_MEMORY_SCOPE_AGENT);
            }
        } else {
            if (tid == 0) {                       // one poller lane per block
                int guard = 0;
                while (__hip_atomic_load(&rel[(blk & 15) * CSTRIDE],
                                         __ATOMIC_RELAXED, __HIP_MEMORY_SCOPE_AGENT) < wrel) {
                    __builtin_amdgcn_s_sleep(4);
                    if (++guard > (1 << 17)) break;   // safety valve
                }
            }
        }
        __syncthreads();
    }
}

// ------------------------------------------------------------- layernorm ----
__global__ void ln_kernel(const float* __restrict__ Fin,
                          const float* __restrict__ gamma,
                          const float* __restrict__ beta,
                          float* __restrict__ out)
{
    const int r = blockIdx.x, tid = threadIdx.x;
    const float* row = Fin + (size_t)r * HDIM;
    float s = 0.f, s2 = 0.f;
    for (int i = tid; i < HDIM; i += 256) { float v = row[i]; s += v; s2 += v * v; }
    for (int off = 32; off; off >>= 1) {
        s  += __shfl_down(s,  off, 64);
        s2 += __shfl_down(s2, off, 64);
    }
    __shared__ float rs[4], rs2[4];
    __shared__ float mu_s, rstd_s;
    if ((tid & 63) == 0) { rs[tid >> 6] = s; rs2[tid >> 6] = s2; }
    __syncthreads();
    if (tid == 0) {
        float S1 = rs[0] + rs[1] + rs[2] + rs[3];
        float S2 = rs2[0] + rs2[1] + rs2[2] + rs2[3];
        float mu = S1 / (float)HDIM;
        float var = S2 / (float)HDIM - mu * mu;
        mu_s = mu; rstd_s = rsqrtf(var + 1e-5f);
    }
    __syncthreads();
    float mu = mu_s, rstd = rstd_s;
    for (int i = tid; i < HDIM; i += 256)
        out[(size_t)r * HDIM + i] = (row[i] - mu) * rstd * gamma[i] + beta[i];
}

// ----------------------------------------------------------------- launch ---
extern "C" void kernel_launch(void* const* d_in, const int* in_sizes, int n_in,
                              void* d_out, int out_size, void* d_ws, size_t ws_size,
                              hipStream_t stream)
{
    const int*   x     = (const int*)d_in[0];
    const float* embed = (const float*)d_in[1];
    const float* Win0  = (const float*)d_in[2];
    const float* WinR  = (const float*)d_in[3];
    const float* Rst   = (const float*)d_in[4];
    const float* gamma = (const float*)d_in[5];
    const float* beta  = (const float*)d_in[6];
    float* out = (float*)d_out;

    char* ws = (char*)d_ws;
    unsigned* cnt = (unsigned*)ws;                    // 16 lines (arrive)
    unsigned* rel = cnt + 16 * CSTRIDE;               // 16 lines (release)
    float* S   = (float*)(ws + 8192);                                // 1MB
    float* Fin = S + S_ELEMS;                                        // 0.5MB
    float* xe  = Fin + FIN_ELEMS;                                    // 16.8MB

    hipMemsetAsync(ws, 0, 8192 + (size_t)S_ELEMS * 4, stream);       // flags+states
    gather_kernel   <<<TT,   256, 0, stream>>>(x, embed, xe);
    reservoir_kernel<<<NBLK, 512, 0, stream>>>(Win0, WinR, Rst, xe, S, Fin, cnt, rel);
    ln_kernel       <<<BB,   256, 0, stream>>>(Fin, gamma, beta, out);
}